// Round 8
// baseline (286.421 us; speedup 1.0000x reference)
//
#include <hip/hip_runtime.h>
#include <hip/hip_bf16.h>
#include <stdint.h>

typedef __hip_bfloat16 bf16;
typedef __attribute__((ext_vector_type(8))) short short8;   // 8 bf16
typedef __attribute__((ext_vector_type(4))) float f32x4;

#define QSCALE 0.18033688011f   // 0.125 * log2(e), folded into Q at gemm0

// ---- 1-instr helpers ----
__device__ __forceinline__ float fast_exp2(float x) {
#if __has_builtin(__builtin_amdgcn_exp2f)
  return __builtin_amdgcn_exp2f(x);
#else
  return exp2f(x);
#endif
}

__device__ __forceinline__ uint32_t pack2_bf16(float a, float b) {
#if __has_builtin(__builtin_amdgcn_cvt_pk_bf16_f32)
  typedef __attribute__((ext_vector_type(2))) __bf16 bf16x2;
  bf16x2 v = __builtin_amdgcn_cvt_pk_bf16_f32(a, b);
  return __builtin_bit_cast(uint32_t, v);
#else
  uint32_t ua = __builtin_bit_cast(uint32_t, a);
  uint32_t ub = __builtin_bit_cast(uint32_t, b);
  ua += 0x7FFF + ((ua >> 16) & 1);   // RNE
  ub += 0x7FFF + ((ub >> 16) & 1);
  return (ua >> 16) | (ub & 0xFFFF0000u);
#endif
}

// async global->LDS, 16B per lane, LDS dest = wave-uniform base + lane*16
__device__ __forceinline__ void gload_lds16(const bf16* g, bf16* l) {
#if __has_builtin(__builtin_amdgcn_global_load_lds)
  __builtin_amdgcn_global_load_lds(
      (const __attribute__((address_space(1))) void*)(uintptr_t)g,
      (__attribute__((address_space(3))) void*)(uint32_t)(uintptr_t)l,
      16, 0, 0);
#else
  int lane = threadIdx.x & 63;
  *(short8*)(l + lane * 8) = *(const short8*)(g + lane * 8);
#endif
}

// ---- fp32->bf16 transpose tile body (64x64) ----
__device__ __forceinline__ void transpose_tile(const float* __restrict__ in,
                                               bf16* __restrict__ out,
                                               int R, int C, int bx, int by,
                                               bf16 (*t)[72]) {
  const int r0 = by * 64, c0 = bx * 64;
  const int rr = threadIdx.x >> 3, cc = (threadIdx.x & 7) * 8;
#pragma unroll
  for (int rep = 0; rep < 2; ++rep) {
    int y = rr + rep * 32;
    const float* p = in + (size_t)(r0 + y) * C + c0 + cc;
    f32x4 v0 = *(const f32x4*)p;
    f32x4 v1 = *(const f32x4*)(p + 4);
#pragma unroll
    for (int j = 0; j < 4; ++j) {
      t[cc + j][y] = __float2bfloat16(v0[j]);
      t[cc + 4 + j][y] = __float2bfloat16(v1[j]);
    }
  }
  __syncthreads();
#pragma unroll
  for (int rep = 0; rep < 2; ++rep) {
    int y = rr + rep * 32;
    short8 v = *(const short8*)&t[y][cc];
    *(short8*)(out + (size_t)(c0 + y) * R + r0 + cc) = v;
  }
}

// ---- fused prep: x->bf16 (blocks 0..2047), Wqkv^T (2048..2815),
//      Wproj^T (2816..3071) ----
__global__ __launch_bounds__(256)
void prep_k(const float* __restrict__ x, bf16* __restrict__ xb,
            const float* __restrict__ Wqkv, bf16* __restrict__ WtQkv,
            const float* __restrict__ Wproj, bf16* __restrict__ WtP) {
  __shared__ __align__(16) bf16 t[64][72];
  const int bid = blockIdx.x;
  if (bid < 2048) {
    int i = (bid * 256 + threadIdx.x) * 8;
    f32x4 v0 = *(const f32x4*)(x + i);
    f32x4 v1 = *(const f32x4*)(x + i + 4);
    short8 r;
    bf16* rb = (bf16*)&r;
#pragma unroll
    for (int j = 0; j < 4; ++j) {
      rb[j] = __float2bfloat16(v0[j]);
      rb[4 + j] = __float2bfloat16(v1[j]);
    }
    *(short8*)(xb + i) = r;
  } else if (bid < 2048 + 768) {
    int b = bid - 2048;
    transpose_tile(Wqkv, WtQkv, 1024, 3072, b % 48, b / 48, t);
  } else {
    int b = bid - 2816;
    transpose_tile(Wproj, WtP, 1024, 1024, b % 16, b / 16, t);
  }
}

// ---------------- GEMM: C[m][n] = A[m,:]·Bt[n,:] + bias[n] -------------------
// MODE 0 (TM=128): scatter Q (pre-scaled by QSCALE) / K as [bh][t][64] bf16,
//                  V^T as [bh][64][t] bf16 (8B-packed stores).
// MODE 1 (TM=64):  fp32 out row-major [M,Nn].
template <int MODE, int TM>
__global__ __launch_bounds__(256, 2)
void gemm_bt(const bf16* __restrict__ A, const bf16* __restrict__ Bt,
             const float* __restrict__ bias, float* __restrict__ outp,
             bf16* __restrict__ Qd, bf16* __restrict__ Kd, bf16* __restrict__ Vt,
             int M, int Nn, int K) {
  constexpr int MI = TM / 32;
  __shared__ __align__(16) bf16 As[TM * 32];
  __shared__ __align__(16) bf16 Bs[128 * 32];

  const int tid = threadIdx.x;
  const int wave = tid >> 6, lane = tid & 63;
  const int quad = lane >> 4, l16 = lane & 15;
  const int mw = (wave >> 1) * (TM / 2), nw = (wave & 1) * 64;
  const int m_blk = blockIdx.y * TM, n_blk = blockIdx.x * 128;

  f32x4 acc[MI][4];
#pragma unroll
  for (int i = 0; i < MI; ++i)
#pragma unroll
    for (int j = 0; j < 4; ++j) acc[i][j] = (f32x4){0.f, 0.f, 0.f, 0.f};

  const int rowA = lane >> 2, colA = (lane & 3) * 8;
  const int chunkB = wave * 2;
  const bf16* gB = Bt + (size_t)(n_blk + chunkB * 16 + rowA) * K + colA;
  bf16* lB0 = &Bs[chunkB * 16 * 32];
  bf16* lB1 = &Bs[(chunkB + 1) * 16 * 32];

  const int chunkA = (TM == 128) ? wave * 2 : wave;
  const bf16* gA = A + (size_t)(m_blk + chunkA * 16 + rowA) * K + colA;
  bf16* lA0 = &As[chunkA * 16 * 32];
  bf16* lA1 = &As[(chunkA + 1) * 16 * 32];  // unused for TM=64

  for (int kt = 0; kt < K; kt += 32) {
    gload_lds16(gA, lA0);
    if (TM == 128) gload_lds16(gA + 16 * K, lA1);
    gload_lds16(gB, lB0);
    gload_lds16(gB + 16 * K, lB1);
    gA += 32; gB += 32;
    __syncthreads();
    short8 af[MI], bfv[4];
#pragma unroll
    for (int i = 0; i < MI; ++i)
      af[i] = *(const short8*)&As[(mw + i * 16 + l16) * 32 + quad * 8];
#pragma unroll
    for (int j = 0; j < 4; ++j)
      bfv[j] = *(const short8*)&Bs[(nw + j * 16 + l16) * 32 + quad * 8];
#pragma unroll
    for (int i = 0; i < MI; ++i)
#pragma unroll
      for (int j = 0; j < 4; ++j)
        acc[i][j] = __builtin_amdgcn_mfma_f32_16x16x32_bf16(af[i], bfv[j],
                                                            acc[i][j], 0, 0, 0);
    __syncthreads();
  }

#pragma unroll
  for (int j = 0; j < 4; ++j) {
    const int ncol = n_blk + nw + j * 16 + l16;
    const float bval = bias[ncol];
    if (MODE == 0) {
      const int part = ncol >> 10;          // 0:q 1:k 2:v
      const int rem = ncol & 1023;
      const int h = rem >> 6, dh = rem & 63;
#pragma unroll
      for (int i = 0; i < MI; ++i) {
        const int t0 = m_blk + mw + i * 16 + quad * 4;  // C row = quad*4+r
        const int b = t0 >> 11, tt = t0 & 2047;
        const size_t bh = (size_t)(b * 16 + h);
        if (part == 2) {
          uint32_t w0 = pack2_bf16(acc[i][j][0] + bval, acc[i][j][1] + bval);
          uint32_t w1 = pack2_bf16(acc[i][j][2] + bval, acc[i][j][3] + bval);
          uint2 pk; pk.x = w0; pk.y = w1;
          *(uint2*)&Vt[(bh * 64 + dh) * 2048 + tt] = pk;
        } else {
          bf16* dst = (part == 0) ? Qd : Kd;
          const float sc = (part == 0) ? QSCALE : 1.0f;
#pragma unroll
          for (int r = 0; r < 4; ++r)
            dst[(bh * 2048 + tt + r) * 64 + dh] =
                __float2bfloat16((acc[i][j][r] + bval) * sc);
        }
      }
    } else {
#pragma unroll
      for (int i = 0; i < MI; ++i) {
        const int mrow0 = m_blk + mw + i * 16 + quad * 4;
#pragma unroll
        for (int r = 0; r < 4; ++r)
          outp[(size_t)(mrow0 + r) * Nn + ncol] = acc[i][j][r] + bval;
      }
    }
  }
}

// ---------------- flash attention: Qtile=64 (wave=16 q-rows), KVtile=64 ------
// K A-fragments loaded DIRECTLY from global (contiguous 16B per lane) — no
// K staging in LDS. V^T double-buffered in LDS; ONE barrier per iteration.
// S^T = K·Q^T: C col=l16=q, row=quad*4+r=kv. Q pre-scaled; deferred norm.
__global__ __launch_bounds__(256, 4)
void attn_kernel(const bf16* __restrict__ Qg, const bf16* __restrict__ Kg,
                 const bf16* __restrict__ Vt, bf16* __restrict__ yg) {
  __shared__ __align__(16) bf16 Vts[2][64 * 72];
  __shared__ __align__(16) bf16 Ps[64][72];   // [q][kv], wave-private rows

  const int tid = threadIdx.x;
  const int wave = tid >> 6, lane = tid & 63;
  const int quad = lane >> 4, l16 = lane & 15;
  const int m0 = wave * 16;

  const int bx = blockIdx.x;
  const int qt = bx & 31;                // 32 q-tiles of 64
  const int bh = bx >> 5;                // b*16 + h

  const bf16* Qb = Qg + ((size_t)bh * 2048 + qt * 64) * 64;
  const bf16* Kb = Kg + (size_t)bh * 2048 * 64;
  const bf16* Vtb = Vt + (size_t)bh * 64 * 2048;

  short8 qf[2];
#pragma unroll
  for (int kb = 0; kb < 2; ++kb)
    qf[kb] = *(const short8*)(Qb + (size_t)(m0 + l16) * 64 + kb * 32 + quad * 8);

  f32x4 yacc[4];
#pragma unroll
  for (int nb = 0; nb < 4; ++nb) yacc[nb] = (f32x4){0.f, 0.f, 0.f, 0.f};

  float sum_l = 0.f;

  // K fragment base: lane reads K[(kt + i*16 + l16)*64 + kb*32 + quad*8]
  const bf16* Kfp = Kb + (size_t)l16 * 64 + quad * 8;

  // V staging: d-row = tid&63, octets vo and vo+4 (vo = wave)
  const int vdd = tid & 63, vo = tid >> 6;
  const int voff0 = vdd * 72 + (((vo) + (vdd >> 3)) & 7) * 8;
  const int voff1 = vdd * 72 + (((vo + 4) + (vdd >> 3)) & 7) * 8;
  const bf16* Vp0 = Vtb + (size_t)vdd * 2048 + vo * 8;
  const bf16* Vp1 = Vtb + (size_t)vdd * 2048 + (vo + 4) * 8;

  // preamble: K frags tile0 -> regs; V tile0 -> Vts[0]; V tile1 -> regs
  short8 kf[4][2];
#pragma unroll
  for (int i = 0; i < 4; ++i) {
    kf[i][0] = *(const short8*)(Kfp + (size_t)i * 16 * 64);
    kf[i][1] = *(const short8*)(Kfp + (size_t)i * 16 * 64 + 32);
  }
  short8 gv0 = *(const short8*)Vp0;
  short8 gv1 = *(const short8*)Vp1;
  *(short8*)&Vts[0][voff0] = gv0;
  *(short8*)&Vts[0][voff1] = gv1;
  gv0 = *(const short8*)(Vp0 + 64);
  gv1 = *(const short8*)(Vp1 + 64);
  __syncthreads();

  for (int kt = 0; kt < 2048; kt += 64) {
    const int cur = (kt >> 6) & 1;
    const bf16* vcur = Vts[cur];
    bf16* vnxt = (bf16*)Vts[cur ^ 1];

    // ---- S^T[kv][q] = K·Q^T from register K frags ----
    f32x4 st[4];
#pragma unroll
    for (int i = 0; i < 4; ++i) {
      f32x4 a = (f32x4){0.f, 0.f, 0.f, 0.f};
      a = __builtin_amdgcn_mfma_f32_16x16x32_bf16(kf[i][0], qf[0], a, 0, 0, 0);
      a = __builtin_amdgcn_mfma_f32_16x16x32_bf16(kf[i][1], qf[1], a, 0, 0, 0);
      st[i] = a;
    }

    // ---- reload K frags for next tile (VMEM in flight through softmax/PV) --
    if (kt + 64 < 2048) {
      const bf16* kn = Kfp + (size_t)(kt + 64) * 64;
#pragma unroll
      for (int i = 0; i < 4; ++i) {
        kf[i][0] = *(const short8*)(kn + (size_t)i * 16 * 64);
        kf[i][1] = *(const short8*)(kn + (size_t)i * 16 * 64 + 32);
      }
    }

    // ---- deferred softmax: p = exp2(st) ----
    float ssum = 0.f;
#pragma unroll
    for (int i = 0; i < 4; ++i) {
      float p0 = fast_exp2(st[i][0]);
      float p1 = fast_exp2(st[i][1]);
      float p2 = fast_exp2(st[i][2]);
      float p3 = fast_exp2(st[i][3]);
      ssum += (p0 + p1) + (p2 + p3);
      uint2 pk;
      pk.x = pack2_bf16(p0, p1);
      pk.y = pack2_bf16(p2, p3);
      *(uint2*)&Ps[m0 + l16][i * 16 + quad * 4] = pk;
    }
    sum_l += ssum;

    // ---- stage next V tile into the other buffer ----
    if (kt + 64 < 2048) {
      *(short8*)&vnxt[voff0] = gv0;
      *(short8*)&vnxt[voff1] = gv1;
      if (kt + 128 < 2048) {
        gv0 = *(const short8*)(Vp0 + kt + 128);
        gv1 = *(const short8*)(Vp1 + kt + 128);
      }
    }
    // wave-private Ps rows: same-wave LDS write->read ordering suffices
    asm volatile("s_waitcnt lgkmcnt(0)" ::: "memory");

    // ---- Y += P V (reads Vts[cur]) ----
#pragma unroll
    for (int kb = 0; kb < 2; ++kb) {
      short8 pa = *(const short8*)&Ps[m0 + l16][kb * 32 + quad * 8];
#pragma unroll
      for (int nb = 0; nb < 4; ++nb) {
        const int d = nb * 16 + l16;
        short8 vbf = *(const short8*)&vcur[d * 72 +
            (((kb * 4 + quad) + (d >> 3)) & 7) * 8];
        yacc[nb] =
            __builtin_amdgcn_mfma_f32_16x16x32_bf16(pa, vbf, yacc[nb], 0, 0, 0);
      }
    }
    __syncthreads();   // all done reading cur & writing nxt
  }

  sum_l += __shfl_xor(sum_l, 16);
  sum_l += __shfl_xor(sum_l, 32);

  const int b = bh >> 4, h = bh & 15;
  const size_t rowbase = (size_t)b * 2048 + qt * 64;
#pragma unroll
  for (int r = 0; r < 4; ++r) {
    const float lv = __shfl(sum_l, quad * 4 + r, 16);
    const float inv = 1.f / lv;
    const int rr = m0 + quad * 4 + r;
#pragma unroll
    for (int nb = 0; nb < 4; ++nb)
      yg[(rowbase + rr) * 1024 + h * 64 + nb * 16 + l16] =
          __float2bfloat16(yacc[nb][r] * inv);
  }
}

// ---------------- launch ----------------
extern "C" void kernel_launch(void* const* d_in, const int* in_sizes, int n_in,
                              void* d_out, int out_size, void* d_ws, size_t ws_size,
                              hipStream_t stream) {
  const float* x = (const float*)d_in[0];      // [4096, 1024] fp32
  const float* Wqkv = (const float*)d_in[1];   // [1024, 3072] fp32
  const float* bqkv = (const float*)d_in[2];   // [3072] fp32
  const float* Wproj = (const float*)d_in[3];  // [1024, 1024] fp32
  const float* bproj = (const float*)d_in[4];  // [1024] fp32
  float* out = (float*)d_out;                  // [4096, 1024] fp32

  if (ws_size < (size_t)40 * 1024 * 1024) return;

  char* ws = (char*)d_ws;
  bf16* xb    = (bf16*)(ws + 0);             // [4096,1024] = 8 MiB
  bf16* yd    = (bf16*)(ws + 0);             // aliases xb (dead after gemm0)
  bf16* WtQkv = (bf16*)(ws + 8388608);       // [3072,1024] = 6 MiB
  bf16* WtP   = (bf16*)(ws + 14680064);      // [1024,1024] = 2 MiB
  bf16* Qd    = (bf16*)(ws + 16777216);      // [32,2048,64] = 8 MiB (pre-scaled)
  bf16* Kd    = (bf16*)(ws + 25165824);      // 8 MiB
  bf16* Vten  = (bf16*)(ws + 33554432);      // [32,64,2048] = 8 MiB

  prep_k<<<3072, 256, 0, stream>>>(x, xb, Wqkv, WtQkv, Wproj, WtP);
  gemm_bt<0, 128><<<dim3(24, 32), 256, 0, stream>>>(
      xb, WtQkv, bqkv, nullptr, Qd, Kd, Vten, 4096, 3072, 1024);
  attn_kernel<<<dim3(1024), 256, 0, stream>>>(Qd, Kd, Vten, yd);
  gemm_bt<1, 64><<<dim3(8, 64), 256, 0, stream>>>(
      yd, WtP, bproj, out, nullptr, nullptr, nullptr, 4096, 1024, 1024);
}

// Round 9
// 200.643 us; speedup vs baseline: 1.4275x; 1.4275x over previous
//
#include <hip/hip_runtime.h>
#include <hip/hip_bf16.h>
#include <stdint.h>

typedef __hip_bfloat16 bf16;
typedef __attribute__((ext_vector_type(8))) short short8;   // 8 bf16
typedef __attribute__((ext_vector_type(4))) float f32x4;

#define QSCALE 0.18033688011f   // 0.125 * log2(e), folded into Q at gemm0

// ---- 1-instr helpers ----
__device__ __forceinline__ float fast_exp2(float x) {
#if __has_builtin(__builtin_amdgcn_exp2f)
  return __builtin_amdgcn_exp2f(x);
#else
  return exp2f(x);
#endif
}

__device__ __forceinline__ uint32_t pack2_bf16(float a, float b) {
#if __has_builtin(__builtin_amdgcn_cvt_pk_bf16_f32)
  typedef __attribute__((ext_vector_type(2))) __bf16 bf16x2;
  bf16x2 v = __builtin_amdgcn_cvt_pk_bf16_f32(a, b);
  return __builtin_bit_cast(uint32_t, v);
#else
  uint32_t ua = __builtin_bit_cast(uint32_t, a);
  uint32_t ub = __builtin_bit_cast(uint32_t, b);
  ua += 0x7FFF + ((ua >> 16) & 1);   // RNE
  ub += 0x7FFF + ((ub >> 16) & 1);
  return (ua >> 16) | (ub & 0xFFFF0000u);
#endif
}

// async global->LDS, 16B per lane, LDS dest = wave-uniform base + lane*16
__device__ __forceinline__ void gload_lds16(const bf16* g, bf16* l) {
#if __has_builtin(__builtin_amdgcn_global_load_lds)
  __builtin_amdgcn_global_load_lds(
      (const __attribute__((address_space(1))) void*)(uintptr_t)g,
      (__attribute__((address_space(3))) void*)(uint32_t)(uintptr_t)l,
      16, 0, 0);
#else
  int lane = threadIdx.x & 63;
  *(short8*)(l + lane * 8) = *(const short8*)(g + lane * 8);
#endif
}

// LDS-only barrier: cross-wave data here is always LDS, so draining lgkmcnt
// suffices — avoids the compiler's conservative vmcnt(0) at __syncthreads,
// keeping global register-prefetch loads in flight across the barrier.
__device__ __forceinline__ void lds_barrier() {
  asm volatile("s_waitcnt lgkmcnt(0)\n\ts_barrier" ::: "memory");
}

// ---- fp32->bf16 transpose tile body (64x64) ----
__device__ __forceinline__ void transpose_tile(const float* __restrict__ in,
                                               bf16* __restrict__ out,
                                               int R, int C, int bx, int by,
                                               bf16 (*t)[72]) {
  const int r0 = by * 64, c0 = bx * 64;
  const int rr = threadIdx.x >> 3, cc = (threadIdx.x & 7) * 8;
#pragma unroll
  for (int rep = 0; rep < 2; ++rep) {
    int y = rr + rep * 32;
    const float* p = in + (size_t)(r0 + y) * C + c0 + cc;
    f32x4 v0 = *(const f32x4*)p;
    f32x4 v1 = *(const f32x4*)(p + 4);
#pragma unroll
    for (int j = 0; j < 4; ++j) {
      t[cc + j][y] = __float2bfloat16(v0[j]);
      t[cc + 4 + j][y] = __float2bfloat16(v1[j]);
    }
  }
  __syncthreads();
#pragma unroll
  for (int rep = 0; rep < 2; ++rep) {
    int y = rr + rep * 32;
    short8 v = *(const short8*)&t[y][cc];
    *(short8*)(out + (size_t)(c0 + y) * R + r0 + cc) = v;
  }
}

// ---- fused prep: x->bf16 (blocks 0..2047), Wqkv^T (2048..2815),
//      Wproj^T (2816..3071) ----
__global__ __launch_bounds__(256)
void prep_k(const float* __restrict__ x, bf16* __restrict__ xb,
            const float* __restrict__ Wqkv, bf16* __restrict__ WtQkv,
            const float* __restrict__ Wproj, bf16* __restrict__ WtP) {
  __shared__ __align__(16) bf16 t[64][72];
  const int bid = blockIdx.x;
  if (bid < 2048) {
    int i = (bid * 256 + threadIdx.x) * 8;
    f32x4 v0 = *(const f32x4*)(x + i);
    f32x4 v1 = *(const f32x4*)(x + i + 4);
    short8 r;
    bf16* rb = (bf16*)&r;
#pragma unroll
    for (int j = 0; j < 4; ++j) {
      rb[j] = __float2bfloat16(v0[j]);
      rb[4 + j] = __float2bfloat16(v1[j]);
    }
    *(short8*)(xb + i) = r;
  } else if (bid < 2048 + 768) {
    int b = bid - 2048;
    transpose_tile(Wqkv, WtQkv, 1024, 3072, b % 48, b / 48, t);
  } else {
    int b = bid - 2816;
    transpose_tile(Wproj, WtP, 1024, 1024, b % 16, b / 16, t);
  }
}

// ---------------- GEMM: C[m][n] = A[m,:]·Bt[n,:] + bias[n] -------------------
// MODE 0 (TM=128): scatter Q (pre-scaled by QSCALE) / K as [bh][t][64] bf16,
//                  V^T as [bh][64][t] bf16 (8B-packed stores).
// MODE 1 (TM=64):  fp32 out row-major [M,Nn].
template <int MODE, int TM>
__global__ __launch_bounds__(256, 2)
void gemm_bt(const bf16* __restrict__ A, const bf16* __restrict__ Bt,
             const float* __restrict__ bias, float* __restrict__ outp,
             bf16* __restrict__ Qd, bf16* __restrict__ Kd, bf16* __restrict__ Vt,
             int M, int Nn, int K) {
  constexpr int MI = TM / 32;
  __shared__ __align__(16) bf16 As[TM * 32];
  __shared__ __align__(16) bf16 Bs[128 * 32];

  const int tid = threadIdx.x;
  const int wave = tid >> 6, lane = tid & 63;
  const int quad = lane >> 4, l16 = lane & 15;
  const int mw = (wave >> 1) * (TM / 2), nw = (wave & 1) * 64;
  const int m_blk = blockIdx.y * TM, n_blk = blockIdx.x * 128;

  f32x4 acc[MI][4];
#pragma unroll
  for (int i = 0; i < MI; ++i)
#pragma unroll
    for (int j = 0; j < 4; ++j) acc[i][j] = (f32x4){0.f, 0.f, 0.f, 0.f};

  const int rowA = lane >> 2, colA = (lane & 3) * 8;
  const int chunkB = wave * 2;
  const bf16* gB = Bt + (size_t)(n_blk + chunkB * 16 + rowA) * K + colA;
  bf16* lB0 = &Bs[chunkB * 16 * 32];
  bf16* lB1 = &Bs[(chunkB + 1) * 16 * 32];

  const int chunkA = (TM == 128) ? wave * 2 : wave;
  const bf16* gA = A + (size_t)(m_blk + chunkA * 16 + rowA) * K + colA;
  bf16* lA0 = &As[chunkA * 16 * 32];
  bf16* lA1 = &As[(chunkA + 1) * 16 * 32];  // unused for TM=64

  for (int kt = 0; kt < K; kt += 32) {
    gload_lds16(gA, lA0);
    if (TM == 128) gload_lds16(gA + 16 * K, lA1);
    gload_lds16(gB, lB0);
    gload_lds16(gB + 16 * K, lB1);
    gA += 32; gB += 32;
    __syncthreads();
    short8 af[MI], bfv[4];
#pragma unroll
    for (int i = 0; i < MI; ++i)
      af[i] = *(const short8*)&As[(mw + i * 16 + l16) * 32 + quad * 8];
#pragma unroll
    for (int j = 0; j < 4; ++j)
      bfv[j] = *(const short8*)&Bs[(nw + j * 16 + l16) * 32 + quad * 8];
#pragma unroll
    for (int i = 0; i < MI; ++i)
#pragma unroll
      for (int j = 0; j < 4; ++j)
        acc[i][j] = __builtin_amdgcn_mfma_f32_16x16x32_bf16(af[i], bfv[j],
                                                            acc[i][j], 0, 0, 0);
    __syncthreads();
  }

#pragma unroll
  for (int j = 0; j < 4; ++j) {
    const int ncol = n_blk + nw + j * 16 + l16;
    const float bval = bias[ncol];
    if (MODE == 0) {
      const int part = ncol >> 10;          // 0:q 1:k 2:v
      const int rem = ncol & 1023;
      const int h = rem >> 6, dh = rem & 63;
#pragma unroll
      for (int i = 0; i < MI; ++i) {
        const int t0 = m_blk + mw + i * 16 + quad * 4;  // C row = quad*4+r
        const int b = t0 >> 11, tt = t0 & 2047;
        const size_t bh = (size_t)(b * 16 + h);
        if (part == 2) {
          uint32_t w0 = pack2_bf16(acc[i][j][0] + bval, acc[i][j][1] + bval);
          uint32_t w1 = pack2_bf16(acc[i][j][2] + bval, acc[i][j][3] + bval);
          uint2 pk; pk.x = w0; pk.y = w1;
          *(uint2*)&Vt[(bh * 64 + dh) * 2048 + tt] = pk;
        } else {
          bf16* dst = (part == 0) ? Qd : Kd;
          const float sc = (part == 0) ? QSCALE : 1.0f;
#pragma unroll
          for (int r = 0; r < 4; ++r)
            dst[(bh * 2048 + tt + r) * 64 + dh] =
                __float2bfloat16((acc[i][j][r] + bval) * sc);
        }
      }
    } else {
#pragma unroll
      for (int i = 0; i < MI; ++i) {
        const int mrow0 = m_blk + mw + i * 16 + quad * 4;
#pragma unroll
        for (int r = 0; r < 4; ++r)
          outp[(size_t)(mrow0 + r) * Nn + ncol] = acc[i][j][r] + bval;
      }
    }
  }
}

// ---------------- flash attention: Qtile=64, KVtile=64, quadrant split -------
// Wave (qh,kvh) owns q in [qh*32,+32), kv in [kvh*32,+32): K-frag and V-frag
// LDS reads drop 2x vs q-only split (waves no longer replicate full tiles).
// S^T = K·Q^T: C col=l16=q, row=quad*4+r=kv. Q pre-scaled; deferred norm.
// K and V double-buffered in LDS; 2 lgkmcnt-only barriers per iteration.
__global__ __launch_bounds__(256, 3)
void attn_kernel(const bf16* __restrict__ Qg, const bf16* __restrict__ Kg,
                 const bf16* __restrict__ Vt, bf16* __restrict__ yg) {
  __shared__ __align__(16) bf16 Ks[2][64][72];   // 18432 B
  __shared__ __align__(16) bf16 Vts[2][64 * 72]; // 18432 B
  __shared__ __align__(16) bf16 Ps[64][72];      //  9216 B (total 46080)

  const int tid = threadIdx.x;
  const int wave = tid >> 6, lane = tid & 63;
  const int quad = lane >> 4, l16 = lane & 15;
  const int qh = wave & 1, kvh = wave >> 1;

  const int bx = blockIdx.x;
  const int qt = bx & 31;                // 32 q-tiles of 64
  const int bh = bx >> 5;                // b*16 + h

  const bf16* Qb = Qg + ((size_t)bh * 2048 + qt * 64) * 64;
  const bf16* Kb = Kg + (size_t)bh * 2048 * 64;
  const bf16* Vtb = Vt + (size_t)bh * 64 * 2048;

  // Q fragments (B-operand for S^T): qf[qblk][kb]
  short8 qf[2][2];
#pragma unroll
  for (int qblk = 0; qblk < 2; ++qblk)
#pragma unroll
    for (int kb = 0; kb < 2; ++kb)
      qf[qblk][kb] = *(const short8*)(
          Qb + (size_t)(qh * 32 + qblk * 16 + l16) * 64 + kb * 32 + quad * 8);

  f32x4 yacc[2][4];
#pragma unroll
  for (int qblk = 0; qblk < 2; ++qblk)
#pragma unroll
    for (int dblk = 0; dblk < 4; ++dblk)
      yacc[qblk][dblk] = (f32x4){0.f, 0.f, 0.f, 0.f};
  float sum_l[2] = {0.f, 0.f};

  // staging indices (256 threads cover the 64x64 tiles)
  const int kr = tid >> 3, kc = (tid & 7) * 8;
  const int vdd = tid & 63, vo = tid >> 6;
  const int voff0 = vdd * 72 + (((vo) + (vdd >> 3)) & 7) * 8;
  const int voff1 = vdd * 72 + (((vo + 4) + (vdd >> 3)) & 7) * 8;
  const bf16* Kp0 = Kb + (size_t)kr * 64 + kc;
  const bf16* Kp1 = Kb + (size_t)(kr + 32) * 64 + kc;
  const bf16* Vp0 = Vtb + (size_t)vdd * 2048 + vo * 8;
  const bf16* Vp1 = Vtb + (size_t)vdd * 2048 + (vo + 4) * 8;

  // preamble: tile0 -> buf0; tile1 -> regs
  {
    short8 a = *(const short8*)Kp0;
    short8 b = *(const short8*)Kp1;
    short8 c = *(const short8*)Vp0;
    short8 d = *(const short8*)Vp1;
    *(short8*)&Ks[0][kr][kc] = a;
    *(short8*)&Ks[0][kr + 32][kc] = b;
    *(short8*)&Vts[0][voff0] = c;
    *(short8*)&Vts[0][voff1] = d;
  }
  short8 gk0 = *(const short8*)(Kp0 + (size_t)64 * 64);
  short8 gk1 = *(const short8*)(Kp1 + (size_t)64 * 64);
  short8 gv0 = *(const short8*)(Vp0 + 64);
  short8 gv1 = *(const short8*)(Vp1 + 64);
  __syncthreads();

  for (int kt = 0; kt < 2048; kt += 64) {
    const int cur = (kt >> 6) & 1;

    // 1. commit tile kt+64 into nxt buffers; 2. prefetch kt+128 into regs
    if (kt + 64 < 2048) {
      *(short8*)&Ks[cur ^ 1][kr][kc] = gk0;
      *(short8*)&Ks[cur ^ 1][kr + 32][kc] = gk1;
      *(short8*)&Vts[cur ^ 1][voff0] = gv0;
      *(short8*)&Vts[cur ^ 1][voff1] = gv1;
      if (kt + 128 < 2048) {
        gk0 = *(const short8*)(Kp0 + (size_t)(kt + 128) * 64);
        gk1 = *(const short8*)(Kp1 + (size_t)(kt + 128) * 64);
        gv0 = *(const short8*)(Vp0 + kt + 128);
        gv1 = *(const short8*)(Vp1 + kt + 128);
      }
    }

    // 3. S^T quadrant: st[qblk][kvblk] over q-half x kv-half
    f32x4 st[2][2];
#pragma unroll
    for (int kvblk = 0; kvblk < 2; ++kvblk) {
      const int krow = kvh * 32 + kvblk * 16 + l16;
      short8 kf0 = *(const short8*)&Ks[cur][krow][quad * 8];
      short8 kf1 = *(const short8*)&Ks[cur][krow][32 + quad * 8];
#pragma unroll
      for (int qblk = 0; qblk < 2; ++qblk) {
        f32x4 a = (f32x4){0.f, 0.f, 0.f, 0.f};
        a = __builtin_amdgcn_mfma_f32_16x16x32_bf16(kf0, qf[qblk][0], a, 0, 0, 0);
        a = __builtin_amdgcn_mfma_f32_16x16x32_bf16(kf1, qf[qblk][1], a, 0, 0, 0);
        st[qblk][kvblk] = a;
      }
    }

    // 4. deferred softmax: p = exp2(st); write P quadrant to Ps
#pragma unroll
    for (int qblk = 0; qblk < 2; ++qblk) {
      float ssum = 0.f;
#pragma unroll
      for (int kvblk = 0; kvblk < 2; ++kvblk) {
        float p0 = fast_exp2(st[qblk][kvblk][0]);
        float p1 = fast_exp2(st[qblk][kvblk][1]);
        float p2 = fast_exp2(st[qblk][kvblk][2]);
        float p3 = fast_exp2(st[qblk][kvblk][3]);
        ssum += (p0 + p1) + (p2 + p3);
        uint2 pk;
        pk.x = pack2_bf16(p0, p1);
        pk.y = pack2_bf16(p2, p3);
        *(uint2*)&Ps[qh * 32 + qblk * 16 + l16]
                    [kvh * 32 + kvblk * 16 + quad * 4] = pk;
      }
      sum_l[qblk] += ssum;
    }

    // 5. Ps is cross-wave for PV -> LDS barrier (no vmcnt drain)
    lds_barrier();

    // 6. Y += P V over this wave's kv-half
    short8 vbf[4];
#pragma unroll
    for (int dblk = 0; dblk < 4; ++dblk) {
      const int d = dblk * 16 + l16;
      vbf[dblk] = *(const short8*)&Vts[cur][d * 72 +
          (((kvh * 4 + quad) + (d >> 3)) & 7) * 8];
    }
#pragma unroll
    for (int qblk = 0; qblk < 2; ++qblk) {
      short8 pa = *(const short8*)&Ps[qh * 32 + qblk * 16 + l16]
                                     [kvh * 32 + quad * 8];
#pragma unroll
      for (int dblk = 0; dblk < 4; ++dblk)
        yacc[qblk][dblk] = __builtin_amdgcn_mfma_f32_16x16x32_bf16(
            pa, vbf[dblk], yacc[qblk][dblk], 0, 0, 0);
    }

    // 7. protect cur buffers (next commit) and Ps (next write)
    lds_barrier();
  }

  // ---- reductions: quads within wave, then kv-halves across waves ----
#pragma unroll
  for (int qblk = 0; qblk < 2; ++qblk) {
    sum_l[qblk] += __shfl_xor(sum_l[qblk], 16);
    sum_l[qblk] += __shfl_xor(sum_l[qblk], 32);
  }
  __syncthreads();
  float* red = (float*)&Ks[0][0][0];        // 16 KiB scratch (fits in Ks)
  float* sred = (float*)&Ps[0][0];          // 256 B
  if (kvh == 1) {
#pragma unroll
    for (int qblk = 0; qblk < 2; ++qblk) {
#pragma unroll
      for (int dblk = 0; dblk < 4; ++dblk) {
        const int f = (qh * 2 + qblk) * 4 + dblk;
        *(f32x4*)&red[(f * 64 + quad * 16 + l16) * 4] = yacc[qblk][dblk];
      }
      if (quad == 0) sred[(qh * 2 + qblk) * 16 + l16] = sum_l[qblk];
    }
  }
  __syncthreads();
  if (kvh == 0) {
    const int b = bh >> 4, h = bh & 15;
    const size_t rowbase = (size_t)b * 2048 + qt * 64;
#pragma unroll
    for (int qblk = 0; qblk < 2; ++qblk) {
      sum_l[qblk] += sred[(qh * 2 + qblk) * 16 + l16];
#pragma unroll
      for (int dblk = 0; dblk < 4; ++dblk) {
        const int f = (qh * 2 + qblk) * 4 + dblk;
        f32x4 o = *(const f32x4*)&red[(f * 64 + quad * 16 + l16) * 4];
#pragma unroll
        for (int r = 0; r < 4; ++r) yacc[qblk][dblk][r] += o[r];
      }
#pragma unroll
      for (int r = 0; r < 4; ++r) {
        const float lv = __shfl(sum_l[qblk], quad * 4 + r, 16);
        const float inv = 1.f / lv;
        const int rr = qh * 32 + qblk * 16 + quad * 4 + r;
#pragma unroll
        for (int dblk = 0; dblk < 4; ++dblk)
          yg[(rowbase + rr) * 1024 + h * 64 + dblk * 16 + l16] =
              __float2bfloat16(yacc[qblk][dblk][r] * inv);
      }
    }
  }
}

// ---------------- launch ----------------
extern "C" void kernel_launch(void* const* d_in, const int* in_sizes, int n_in,
                              void* d_out, int out_size, void* d_ws, size_t ws_size,
                              hipStream_t stream) {
  const float* x = (const float*)d_in[0];      // [4096, 1024] fp32
  const float* Wqkv = (const float*)d_in[1];   // [1024, 3072] fp32
  const float* bqkv = (const float*)d_in[2];   // [3072] fp32
  const float* Wproj = (const float*)d_in[3];  // [1024, 1024] fp32
  const float* bproj = (const float*)d_in[4];  // [1024] fp32
  float* out = (float*)d_out;                  // [4096, 1024] fp32

  if (ws_size < (size_t)40 * 1024 * 1024) return;

  char* ws = (char*)d_ws;
  bf16* xb    = (bf16*)(ws + 0);             // [4096,1024] = 8 MiB
  bf16* yd    = (bf16*)(ws + 0);             // aliases xb (dead after gemm0)
  bf16* WtQkv = (bf16*)(ws + 8388608);       // [3072,1024] = 6 MiB
  bf16* WtP   = (bf16*)(ws + 14680064);      // [1024,1024] = 2 MiB
  bf16* Qd    = (bf16*)(ws + 16777216);      // [32,2048,64] = 8 MiB (pre-scaled)
  bf16* Kd    = (bf16*)(ws + 25165824);      // 8 MiB
  bf16* Vten  = (bf16*)(ws + 33554432);      // [32,64,2048] = 8 MiB

  prep_k<<<3072, 256, 0, stream>>>(x, xb, Wqkv, WtQkv, Wproj, WtP);
  gemm_bt<0, 128><<<dim3(24, 32), 256, 0, stream>>>(
      xb, WtQkv, bqkv, nullptr, Qd, Kd, Vten, 4096, 3072, 1024);
  attn_kernel<<<dim3(1024), 256, 0, stream>>>(Qd, Kd, Vten, yd);
  gemm_bt<1, 64><<<dim3(8, 64), 256, 0, stream>>>(
      yd, WtP, bproj, out, nullptr, nullptr, nullptr, 4096, 1024, 1024);
}

// Round 11
// 195.849 us; speedup vs baseline: 1.4625x; 1.0245x over previous
//
#include <hip/hip_runtime.h>
#include <hip/hip_bf16.h>
#include <stdint.h>

typedef __hip_bfloat16 bf16;
typedef __attribute__((ext_vector_type(8))) short short8;   // 8 bf16
typedef __attribute__((ext_vector_type(4))) float f32x4;

#define QSCALE 0.18033688011f   // 0.125 * log2(e), folded into Q at gemm0

// ---- 1-instr helpers ----
__device__ __forceinline__ float fast_exp2(float x) {
#if __has_builtin(__builtin_amdgcn_exp2f)
  return __builtin_amdgcn_exp2f(x);
#else
  return exp2f(x);
#endif
}

__device__ __forceinline__ uint32_t pack2_bf16(float a, float b) {
#if __has_builtin(__builtin_amdgcn_cvt_pk_bf16_f32)
  typedef __attribute__((ext_vector_type(2))) __bf16 bf16x2;
  bf16x2 v = __builtin_amdgcn_cvt_pk_bf16_f32(a, b);
  return __builtin_bit_cast(uint32_t, v);
#else
  uint32_t ua = __builtin_bit_cast(uint32_t, a);
  uint32_t ub = __builtin_bit_cast(uint32_t, b);
  ua += 0x7FFF + ((ua >> 16) & 1);   // RNE
  ub += 0x7FFF + ((ub >> 16) & 1);
  return (ua >> 16) | (ub & 0xFFFF0000u);
#endif
}

// async global->LDS, 16B per lane, LDS dest = wave-uniform base + lane*16
__device__ __forceinline__ void gload_lds16(const bf16* g, bf16* l) {
#if __has_builtin(__builtin_amdgcn_global_load_lds)
  __builtin_amdgcn_global_load_lds(
      (const __attribute__((address_space(1))) void*)(uintptr_t)g,
      (__attribute__((address_space(3))) void*)(uint32_t)(uintptr_t)l,
      16, 0, 0);
#else
  int lane = threadIdx.x & 63;
  *(short8*)(l + lane * 8) = *(const short8*)(g + lane * 8);
#endif
}

// LDS-only barrier (no vmcnt drain): keeps global prefetch loads in flight.
__device__ __forceinline__ void lds_barrier() {
  asm volatile("s_waitcnt lgkmcnt(0)\n\ts_barrier" ::: "memory");
}

// ---- fp32->bf16 transpose tile body (64x64) ----
__device__ __forceinline__ void transpose_tile(const float* __restrict__ in,
                                               bf16* __restrict__ out,
                                               int R, int C, int bx, int by,
                                               bf16 (*t)[72]) {
  const int r0 = by * 64, c0 = bx * 64;
  const int rr = threadIdx.x >> 3, cc = (threadIdx.x & 7) * 8;
#pragma unroll
  for (int rep = 0; rep < 2; ++rep) {
    int y = rr + rep * 32;
    const float* p = in + (size_t)(r0 + y) * C + c0 + cc;
    f32x4 v0 = *(const f32x4*)p;
    f32x4 v1 = *(const f32x4*)(p + 4);
#pragma unroll
    for (int j = 0; j < 4; ++j) {
      t[cc + j][y] = __float2bfloat16(v0[j]);
      t[cc + 4 + j][y] = __float2bfloat16(v1[j]);
    }
  }
  __syncthreads();
#pragma unroll
  for (int rep = 0; rep < 2; ++rep) {
    int y = rr + rep * 32;
    short8 v = *(const short8*)&t[y][cc];
    *(short8*)(out + (size_t)(c0 + y) * R + r0 + cc) = v;
  }
}

// ---- fused prep: x->bf16 (blocks 0..2047), Wqkv^T (2048..2815),
//      Wproj^T (2816..3071) ----
__global__ __launch_bounds__(256)
void prep_k(const float* __restrict__ x, bf16* __restrict__ xb,
            const float* __restrict__ Wqkv, bf16* __restrict__ WtQkv,
            const float* __restrict__ Wproj, bf16* __restrict__ WtP) {
  __shared__ __align__(16) bf16 t[64][72];
  const int bid = blockIdx.x;
  if (bid < 2048) {
    int i = (bid * 256 + threadIdx.x) * 8;
    f32x4 v0 = *(const f32x4*)(x + i);
    f32x4 v1 = *(const f32x4*)(x + i + 4);
    short8 r;
    bf16* rb = (bf16*)&r;
#pragma unroll
    for (int j = 0; j < 4; ++j) {
      rb[j] = __float2bfloat16(v0[j]);
      rb[4 + j] = __float2bfloat16(v1[j]);
    }
    *(short8*)(xb + i) = r;
  } else if (bid < 2048 + 768) {
    int b = bid - 2048;
    transpose_tile(Wqkv, WtQkv, 1024, 3072, b % 48, b / 48, t);
  } else {
    int b = bid - 2816;
    transpose_tile(Wproj, WtP, 1024, 1024, b % 16, b / 16, t);
  }
}

// ---------------- GEMM: C[m][n] = A[m,:]·Bt[n,:] + bias[n] -------------------
// MODE 0 (TM=128): LDS-transposed coalesced epilogue -> Q (xQSCALE) / K as
//                  [bh][t][64], V^T as [bh][64][t]. All 16B/lane stores.
// MODE 1 (TM=64):  fp32 out row-major [M,Nn].
template <int MODE, int TM>
__global__ __launch_bounds__(256, 2)
void gemm_bt(const bf16* __restrict__ A, const bf16* __restrict__ Bt,
             const float* __restrict__ bias, float* __restrict__ outp,
             bf16* __restrict__ Qd, bf16* __restrict__ Kd, bf16* __restrict__ Vt,
             int M, int Nn, int K) {
  constexpr int MI = TM / 32;
  // staging (TM*32 + 4096 el) and MODE-0 epilogue (<=9216 el) share this pool
  __shared__ __align__(16) bf16 smem[(TM == 128) ? 9216 : 6144];
  bf16* As = smem;
  bf16* Bs = smem + TM * 32;

  const int tid = threadIdx.x;
  const int wave = tid >> 6, lane = tid & 63;
  const int quad = lane >> 4, l16 = lane & 15;
  const int mw = (wave >> 1) * (TM / 2), nw = (wave & 1) * 64;
  const int m_blk = blockIdx.y * TM, n_blk = blockIdx.x * 128;

  f32x4 acc[MI][4];
#pragma unroll
  for (int i = 0; i < MI; ++i)
#pragma unroll
    for (int j = 0; j < 4; ++j) acc[i][j] = (f32x4){0.f, 0.f, 0.f, 0.f};

  const int rowA = lane >> 2, colA = (lane & 3) * 8;
  const int chunkB = wave * 2;
  const bf16* gB = Bt + (size_t)(n_blk + chunkB * 16 + rowA) * K + colA;
  bf16* lB0 = &Bs[chunkB * 16 * 32];
  bf16* lB1 = &Bs[(chunkB + 1) * 16 * 32];

  const int chunkA = (TM == 128) ? wave * 2 : wave;
  const bf16* gA = A + (size_t)(m_blk + chunkA * 16 + rowA) * K + colA;
  bf16* lA0 = &As[chunkA * 16 * 32];
  bf16* lA1 = &As[(chunkA + 1) * 16 * 32];  // unused for TM=64

  for (int kt = 0; kt < K; kt += 32) {
    gload_lds16(gA, lA0);
    if (TM == 128) gload_lds16(gA + 16 * K, lA1);
    gload_lds16(gB, lB0);
    gload_lds16(gB + 16 * K, lB1);
    gA += 32; gB += 32;
    __syncthreads();
    short8 af[MI], bfv[4];
#pragma unroll
    for (int i = 0; i < MI; ++i)
      af[i] = *(const short8*)&As[(mw + i * 16 + l16) * 32 + quad * 8];
#pragma unroll
    for (int j = 0; j < 4; ++j)
      bfv[j] = *(const short8*)&Bs[(nw + j * 16 + l16) * 32 + quad * 8];
#pragma unroll
    for (int i = 0; i < MI; ++i)
#pragma unroll
      for (int j = 0; j < 4; ++j)
        acc[i][j] = __builtin_amdgcn_mfma_f32_16x16x32_bf16(af[i], bfv[j],
                                                            acc[i][j], 0, 0, 0);
    __syncthreads();
  }

  if (MODE == 0) {
    // per-j bias for this wave's columns
    float bval[4];
#pragma unroll
    for (int j = 0; j < 4; ++j) bval[j] = bias[n_blk + nw + j * 16 + l16];

    const int part = n_blk >> 10;          // 0:q 1:k 2:v (block-uniform)
    const int b = m_blk >> 11;
    const int tloc = m_blk & 2047;
    const int h0 = (n_blk & 1023) >> 6;

#pragma unroll
    for (int p = 0; p < 2; ++p) {          // feature halves (64 cols = 1 head)
      __syncthreads();
      if ((nw >> 6) == p) {
        if (part == 2) {
          // V half-tile as [64 d][136 t], 8B-packed writes (r -> t contiguous)
#pragma unroll
          for (int i = 0; i < MI; ++i)
#pragma unroll
            for (int j = 0; j < 4; ++j) {
              const int dh = j * 16 + l16;
              const int t0 = mw + i * 16 + quad * 4;
              uint2 pk;
              pk.x = pack2_bf16(acc[i][j][0] + bval[j], acc[i][j][1] + bval[j]);
              pk.y = pack2_bf16(acc[i][j][2] + bval[j], acc[i][j][3] + bval[j]);
              *(uint2*)&smem[dh * 136 + t0] = pk;
            }
        } else {
          // Q/K half-tile as [128 t][72 d] (stride-72: conflict-free writes)
          const float sc = (part == 0) ? QSCALE : 1.0f;
#pragma unroll
          for (int i = 0; i < MI; ++i)
#pragma unroll
            for (int j = 0; j < 4; ++j) {
              const int d = j * 16 + l16;
              const int t0 = mw + i * 16 + quad * 4;
#pragma unroll
              for (int r = 0; r < 4; ++r)
                smem[(t0 + r) * 72 + d] =
                    __float2bfloat16((acc[i][j][r] + bval[j]) * sc);
            }
        }
      }
      __syncthreads();
      const size_t bh = (size_t)(b * 16 + h0 + p);
      if (part == 2) {
#pragma unroll
        for (int it = 0; it < 4; ++it) {
          const int dl = (tid >> 4) + it * 16;
          const int t8 = (tid & 15) * 8;
          short8 v = *(const short8*)&smem[dl * 136 + t8];
          *(short8*)&Vt[(bh * 64 + dl) * 2048 + tloc + t8] = v;
        }
      } else {
        bf16* dst = (part == 0) ? Qd : Kd;
#pragma unroll
        for (int it = 0; it < 4; ++it) {
          const int row = (tid >> 3) + it * 32;
          const int col8 = (tid & 7) * 8;
          short8 v = *(const short8*)&smem[row * 72 + col8];
          *(short8*)&dst[(bh * 2048 + tloc + row) * 64 + col8] = v;
        }
      }
    }
  } else {
#pragma unroll
    for (int j = 0; j < 4; ++j) {
      const int ncol = n_blk + nw + j * 16 + l16;
      const float bval = bias[ncol];
#pragma unroll
      for (int i = 0; i < MI; ++i) {
        const int mrow0 = m_blk + mw + i * 16 + quad * 4;
#pragma unroll
        for (int r = 0; r < 4; ++r)
          outp[(size_t)(mrow0 + r) * Nn + ncol] = acc[i][j][r] + bval;
      }
    }
  }
}

// ---------------- flash attention: Qtile=64, KVtile=64, quadrant split -------
// Wave (qh,kvh) owns q-half x kv-half. S^T = K·Q^T: C col=l16=q, row=kv.
// Q pre-scaled; deferred normalization. K SINGLE-buffered (commit after the
// mid-loop barrier), V double-buffered. LDS 36864B -> 4 blocks/CU.
__global__ __launch_bounds__(256, 4)
void attn_kernel(const bf16* __restrict__ Qg, const bf16* __restrict__ Kg,
                 const bf16* __restrict__ Vt, bf16* __restrict__ yg) {
  __shared__ __align__(16) bf16 Ks[64][72];      //  9216 B
  __shared__ __align__(16) bf16 Vts[2][64 * 72]; // 18432 B
  __shared__ __align__(16) bf16 Ps[64][72];      //  9216 B (total 36864)

  const int tid = threadIdx.x;
  const int wave = tid >> 6, lane = tid & 63;
  const int quad = lane >> 4, l16 = lane & 15;
  const int qh = wave & 1, kvh = wave >> 1;

  const int bx = blockIdx.x;
  const int qt = bx & 31;                // 32 q-tiles of 64
  const int bh = bx >> 5;                // b*16 + h

  const bf16* Qb = Qg + ((size_t)bh * 2048 + qt * 64) * 64;
  const bf16* Kb = Kg + (size_t)bh * 2048 * 64;
  const bf16* Vtb = Vt + (size_t)bh * 64 * 2048;

  short8 qf[2][2];
#pragma unroll
  for (int qblk = 0; qblk < 2; ++qblk)
#pragma unroll
    for (int kb = 0; kb < 2; ++kb)
      qf[qblk][kb] = *(const short8*)(
          Qb + (size_t)(qh * 32 + qblk * 16 + l16) * 64 + kb * 32 + quad * 8);

  f32x4 yacc[2][4];
#pragma unroll
  for (int qblk = 0; qblk < 2; ++qblk)
#pragma unroll
    for (int dblk = 0; dblk < 4; ++dblk)
      yacc[qblk][dblk] = (f32x4){0.f, 0.f, 0.f, 0.f};
  float sum_l[2] = {0.f, 0.f};

  const int kr = tid >> 3, kc = (tid & 7) * 8;
  const int vdd = tid & 63, vo = tid >> 6;
  const int voff0 = vdd * 72 + (((vo) + (vdd >> 3)) & 7) * 8;
  const int voff1 = vdd * 72 + (((vo + 4) + (vdd >> 3)) & 7) * 8;
  const bf16* Kp0 = Kb + (size_t)kr * 64 + kc;
  const bf16* Kp1 = Kb + (size_t)(kr + 32) * 64 + kc;
  const bf16* Vp0 = Vtb + (size_t)vdd * 2048 + vo * 8;
  const bf16* Vp1 = Vtb + (size_t)vdd * 2048 + (vo + 4) * 8;

  // preamble: K/V tile0 -> LDS; K/V tile1 -> regs
  {
    short8 a = *(const short8*)Kp0;
    short8 b = *(const short8*)Kp1;
    short8 c = *(const short8*)Vp0;
    short8 d = *(const short8*)Vp1;
    *(short8*)&Ks[kr][kc] = a;
    *(short8*)&Ks[kr + 32][kc] = b;
    *(short8*)&Vts[0][voff0] = c;
    *(short8*)&Vts[0][voff1] = d;
  }
  short8 gk0 = *(const short8*)(Kp0 + (size_t)64 * 64);
  short8 gk1 = *(const short8*)(Kp1 + (size_t)64 * 64);
  short8 gv0 = *(const short8*)(Vp0 + 64);
  short8 gv1 = *(const short8*)(Vp1 + 64);
  __syncthreads();

  for (int kt = 0; kt < 2048; kt += 64) {
    const int cur = (kt >> 6) & 1;

    // 1. commit next V tile; prefetch V kt+128
    if (kt + 64 < 2048) {
      *(short8*)&Vts[cur ^ 1][voff0] = gv0;
      *(short8*)&Vts[cur ^ 1][voff1] = gv1;
      if (kt + 128 < 2048) {
        gv0 = *(const short8*)(Vp0 + kt + 128);
        gv1 = *(const short8*)(Vp1 + kt + 128);
      }
    }

    // 2. S^T quadrant from Ks (tile kt)
    f32x4 st[2][2];
#pragma unroll
    for (int kvblk = 0; kvblk < 2; ++kvblk) {
      const int krow = kvh * 32 + kvblk * 16 + l16;
      short8 kf0 = *(const short8*)&Ks[krow][quad * 8];
      short8 kf1 = *(const short8*)&Ks[krow][32 + quad * 8];
#pragma unroll
      for (int qblk = 0; qblk < 2; ++qblk) {
        f32x4 a = (f32x4){0.f, 0.f, 0.f, 0.f};
        a = __builtin_amdgcn_mfma_f32_16x16x32_bf16(kf0, qf[qblk][0], a, 0, 0, 0);
        a = __builtin_amdgcn_mfma_f32_16x16x32_bf16(kf1, qf[qblk][1], a, 0, 0, 0);
        st[qblk][kvblk] = a;
      }
    }

    // 3. deferred softmax -> Ps quadrant
#pragma unroll
    for (int qblk = 0; qblk < 2; ++qblk) {
      float ssum = 0.f;
#pragma unroll
      for (int kvblk = 0; kvblk < 2; ++kvblk) {
        float p0 = fast_exp2(st[qblk][kvblk][0]);
        float p1 = fast_exp2(st[qblk][kvblk][1]);
        float p2 = fast_exp2(st[qblk][kvblk][2]);
        float p3 = fast_exp2(st[qblk][kvblk][3]);
        ssum += (p0 + p1) + (p2 + p3);
        uint2 pk;
        pk.x = pack2_bf16(p0, p1);
        pk.y = pack2_bf16(p2, p3);
        *(uint2*)&Ps[qh * 32 + qblk * 16 + l16]
                    [kvh * 32 + kvblk * 16 + quad * 4] = pk;
      }
      sum_l[qblk] += ssum;
    }

    // 4. barrier: Ks reads + Ps writes done across waves
    lds_barrier();

    // 5. commit next K tile into the single Ks buffer; prefetch K kt+128
    if (kt + 64 < 2048) {
      *(short8*)&Ks[kr][kc] = gk0;
      *(short8*)&Ks[kr + 32][kc] = gk1;
      if (kt + 128 < 2048) {
        gk0 = *(const short8*)(Kp0 + (size_t)(kt + 128) * 64);
        gk1 = *(const short8*)(Kp1 + (size_t)(kt + 128) * 64);
      }
    }

    // 6. Y += P V over this wave's kv-half
    short8 vbf[4];
#pragma unroll
    for (int dblk = 0; dblk < 4; ++dblk) {
      const int d = dblk * 16 + l16;
      vbf[dblk] = *(const short8*)&Vts[cur][d * 72 +
          (((kvh * 4 + quad) + (d >> 3)) & 7) * 8];
    }
#pragma unroll
    for (int qblk = 0; qblk < 2; ++qblk) {
      short8 pa = *(const short8*)&Ps[qh * 32 + qblk * 16 + l16]
                                     [kvh * 32 + quad * 8];
#pragma unroll
      for (int dblk = 0; dblk < 4; ++dblk)
        yacc[qblk][dblk] = __builtin_amdgcn_mfma_f32_16x16x32_bf16(
            pa, vbf[dblk], yacc[qblk][dblk], 0, 0, 0);
    }

    // 7. barrier: Ks commit visible; Vts[cur]/Ps free for next iter
    lds_barrier();
  }

  // ---- reductions: quads within wave, then kv-halves across waves ----
#pragma unroll
  for (int qblk = 0; qblk < 2; ++qblk) {
    sum_l[qblk] += __shfl_xor(sum_l[qblk], 16);
    sum_l[qblk] += __shfl_xor(sum_l[qblk], 32);
  }
  __syncthreads();
  // 16 KiB Y-partial scratch MUST fit its host array: use Vts (18432 B).
  // (R10 bug: this sat at Ks base with Ks only 9216 B -> overflow into
  //  compiler-placed neighbors corrupted the reduction.)
  float* red = (float*)&Vts[0][0];
  float* sred = (float*)&Ps[0][0];          // 256 B
  if (kvh == 1) {
#pragma unroll
    for (int qblk = 0; qblk < 2; ++qblk) {
#pragma unroll
      for (int dblk = 0; dblk < 4; ++dblk) {
        const int f = (qh * 2 + qblk) * 4 + dblk;
        *(f32x4*)&red[(f * 64 + quad * 16 + l16) * 4] = yacc[qblk][dblk];
      }
      if (quad == 0) sred[(qh * 2 + qblk) * 16 + l16] = sum_l[qblk];
    }
  }
  __syncthreads();
  if (kvh == 0) {
    const int b = bh >> 4, h = bh & 15;
    const size_t rowbase = (size_t)b * 2048 + qt * 64;
#pragma unroll
    for (int qblk = 0; qblk < 2; ++qblk) {
      sum_l[qblk] += sred[(qh * 2 + qblk) * 16 + l16];
#pragma unroll
      for (int dblk = 0; dblk < 4; ++dblk) {
        const int f = (qh * 2 + qblk) * 4 + dblk;
        f32x4 o = *(const f32x4*)&red[(f * 64 + quad * 16 + l16) * 4];
#pragma unroll
        for (int r = 0; r < 4; ++r) yacc[qblk][dblk][r] += o[r];
      }
#pragma unroll
      for (int r = 0; r < 4; ++r) {
        const float lv = __shfl(sum_l[qblk], quad * 4 + r, 16);
        const float inv = 1.f / lv;
        const int rr = qh * 32 + qblk * 16 + quad * 4 + r;
#pragma unroll
        for (int dblk = 0; dblk < 4; ++dblk)
          yg[(rowbase + rr) * 1024 + h * 64 + dblk * 16 + l16] =
              __float2bfloat16(yacc[qblk][dblk][r] * inv);
      }
    }
  }
}

// ---------------- launch ----------------
extern "C" void kernel_launch(void* const* d_in, const int* in_sizes, int n_in,
                              void* d_out, int out_size, void* d_ws, size_t ws_size,
                              hipStream_t stream) {
  const float* x = (const float*)d_in[0];      // [4096, 1024] fp32
  const float* Wqkv = (const float*)d_in[1];   // [1024, 3072] fp32
  const float* bqkv = (const float*)d_in[2];   // [3072] fp32
  const float* Wproj = (const float*)d_in[3];  // [1024, 1024] fp32
  const float* bproj = (const float*)d_in[4];  // [1024] fp32
  float* out = (float*)d_out;                  // [4096, 1024] fp32

  if (ws_size < (size_t)40 * 1024 * 1024) return;

  char* ws = (char*)d_ws;
  bf16* xb    = (bf16*)(ws + 0);             // [4096,1024] = 8 MiB
  bf16* yd    = (bf16*)(ws + 0);             // aliases xb (dead after gemm0)
  bf16* WtQkv = (bf16*)(ws + 8388608);       // [3072,1024] = 6 MiB
  bf16* WtP   = (bf16*)(ws + 14680064);      // [1024,1024] = 2 MiB
  bf16* Qd    = (bf16*)(ws + 16777216);      // [32,2048,64] = 8 MiB (pre-scaled)
  bf16* Kd    = (bf16*)(ws + 25165824);      // 8 MiB
  bf16* Vten  = (bf16*)(ws + 33554432);      // [32,64,2048] = 8 MiB

  prep_k<<<3072, 256, 0, stream>>>(x, xb, Wqkv, WtQkv, Wproj, WtP);
  gemm_bt<0, 128><<<dim3(24, 32), 256, 0, stream>>>(
      xb, WtQkv, bqkv, nullptr, Qd, Kd, Vten, 4096, 3072, 1024);
  attn_kernel<<<dim3(1024), 256, 0, stream>>>(Qd, Kd, Vten, yd);
  gemm_bt<1, 64><<<dim3(8, 64), 256, 0, stream>>>(
      yd, WtP, bproj, out, nullptr, nullptr, nullptr, 4096, 1024, 1024);
}